// Round 5
// baseline (21544.247 us; speedup 1.0000x reference)
//
#include <hip/hip_runtime.h>
#include <hip/hip_bf16.h>
#include <hip/hip_fp16.h>

#define BB  512
#define TT  256
#define MM  81
#define HEE 256

// ---- workspace layout (float offsets) ----
#define OFF_W2AH   0          // half2[256 k2][256 j]  encoder p1 weights
#define OFF_WE8    65536      // uint4[169 k2][256 j]  encoder LSTM weights (4 gates x k-pair, fp16)
#define OFF_W2D1   238592     // half2[256 k2][256 j]  decoder p1 weights
#define OFF_WD8    304128     // uint4[129 k2][256 j]  decoder LSTM weights
#define OFF_ATTN   436224     // [512][81] attn_in
#define OFF_ENCW   477696     // [512][256] enc . W_fc[:256]
#define OFF_ENC    608768     // [512][256][256] input_encoded fp32
#define OFF_EPI    34163200   // half[512 b][256 t'][256 h] enc_proj
#define WS_FLOATS  50940416

__device__ __forceinline__ float frcp(float x) { return __builtin_amdgcn_rcpf(x); }
__device__ __forceinline__ float fsig(float x) { return frcp(1.f + __expf(-x)); }
__device__ __forceinline__ float ftanh(float x) { return 1.f - 2.f * frcp(__expf(2.f * x) + 1.f); }

// both-batch gate FMA: uv = (u[ke]b0, u[ke]b1, u[ko]b0, u[ko]b1)
__device__ __forceinline__ void gate_fma(const uint4& wu, const float4& uv, float4& g0, float4& g1) {
  const __half2* wh = reinterpret_cast<const __half2*>(&wu);
  float2 if0 = __half22float2(wh[0]);
  float2 go0 = __half22float2(wh[1]);
  float2 if1 = __half22float2(wh[2]);
  float2 go1 = __half22float2(wh[3]);
  g0.x = fmaf(if0.x, uv.x, fmaf(if1.x, uv.z, g0.x));
  g0.y = fmaf(if0.y, uv.x, fmaf(if1.y, uv.z, g0.y));
  g0.z = fmaf(go0.x, uv.x, fmaf(go1.x, uv.z, g0.z));
  g0.w = fmaf(go0.y, uv.x, fmaf(go1.y, uv.z, g0.w));
  g1.x = fmaf(if0.x, uv.y, fmaf(if1.x, uv.w, g1.x));
  g1.y = fmaf(if0.y, uv.y, fmaf(if1.y, uv.w, g1.y));
  g1.z = fmaf(go0.x, uv.y, fmaf(go1.x, uv.w, g1.z));
  g1.w = fmaf(go0.y, uv.y, fmaf(go1.y, uv.w, g1.w));
}

// ---------------- weight prep ----------------
__global__ void k_prep(const float* __restrict__ W_ah, const float* __restrict__ Wih_e,
                       const float* __restrict__ Whh_e, const float* __restrict__ W_d1,
                       const float* __restrict__ Wih_d, const float* __restrict__ Whh_d,
                       float* __restrict__ ws) {
  int idx = blockIdx.x * 512 + threadIdx.x;
  if (idx < 65536) {
    int k2 = idx >> 8, j = idx & 255;
    ((__half2*)(ws + OFF_W2AH))[idx] =
        __floats2half2_rn(W_ah[j * 512 + 2 * k2], W_ah[j * 512 + 2 * k2 + 1]);
    ((__half2*)(ws + OFF_W2D1))[idx] =
        __floats2half2_rn(W_d1[j * 768 + 2 * k2], W_d1[j * 768 + 2 * k2 + 1]);
  }
  if (idx < 43264) {  // 169*256
    int k2 = idx >> 8, j = idx & 255;
    auto we = [&](int g, int kk) -> float {
      if (kk < 81)  return Wih_e[(g * 256 + j) * 81 + kk];
      if (kk < 337) return Whh_e[(g * 256 + j) * 256 + (kk - 81)];
      return 0.f;
    };
    int ke = 2 * k2, ko = 2 * k2 + 1;
    union { __half2 h[4]; uint4 u; } w;
    w.h[0] = __floats2half2_rn(we(0, ke), we(1, ke));
    w.h[1] = __floats2half2_rn(we(2, ke), we(3, ke));
    w.h[2] = __floats2half2_rn(we(0, ko), we(1, ko));
    w.h[3] = __floats2half2_rn(we(2, ko), we(3, ko));
    ((uint4*)(ws + OFF_WE8))[idx] = w.u;
  }
  if (idx < 33024) {  // 129*256
    int k2 = idx >> 8, j = idx & 255;
    auto wd = [&](int g, int kk) -> float {
      if (kk == 0)  return Wih_d[g * 256 + j];
      if (kk < 257) return Whh_d[(g * 256 + j) * 256 + (kk - 1)];
      return 0.f;
    };
    int ke = 2 * k2, ko = 2 * k2 + 1;
    union { __half2 h[4]; uint4 u; } w;
    w.h[0] = __floats2half2_rn(wd(0, ke), wd(1, ke));
    w.h[1] = __floats2half2_rn(wd(2, ke), wd(3, ke));
    w.h[2] = __floats2half2_rn(wd(0, ko), wd(1, ko));
    w.h[3] = __floats2half2_rn(wd(2, ko), wd(3, ko));
    ((uint4*)(ws + OFF_WD8))[idx] = w.u;
  }
}

// ---------------- attn_in[b][m] ----------------
__global__ void k_attn(const float* __restrict__ x, const float* __restrict__ W_ai,
                       const float* __restrict__ b_ai, float* __restrict__ ws) {
  __shared__ float wai[256];
  const int b = blockIdx.x, tid = threadIdx.x;  // 128 threads
  wai[tid] = W_ai[tid];
  wai[128 + tid] = W_ai[128 + tid];
  __syncthreads();
  if (tid < MM) {
    float acc = b_ai[0];
    const float* xp = x + (size_t)b * TT * MM + tid;
    #pragma unroll 8
    for (int t = 0; t < TT; ++t) acc = fmaf(xp[t * MM], wai[t], acc);
    ws[OFF_ATTN + b * MM + tid] = acc;
  }
}

// ---------------- encoder: 1024 threads, 2 batch rows, 256 steps ----------------
__global__ __launch_bounds__(1024, 2) void k_encoder(
    const float* __restrict__ x, const float* __restrict__ b_ah,
    const float* __restrict__ W_a, const float* __restrict__ b_a,
    const float* __restrict__ bih_e, const float* __restrict__ bhh_e,
    float* __restrict__ ws) {
  __shared__ __align__(16) float arena[8192];   // pp(2048) / scp(1536) / gp(8192 as float4)
  __shared__ __align__(16) float hcat[1024];    // [h;c] packed addr = 2k + b
  __shared__ __align__(16) float ubuf[680];     // packed: (k>>1)*4+(k&1)*2+b, k in [0,338)
  __shared__ __align__(16) float hpb[512];      // hid_proj packed 2t+b
  __shared__ __align__(16) float wa2[256];
  const int tid = threadIdx.x;
  const int j = tid & 255, q = tid >> 8;
  const int b0 = blockIdx.x * 2, b1 = b0 + 1;

  if (tid < 256) wa2[tid] = W_a[tid];
  hcat[tid] = 0.f;
  if (tid < 680) ubuf[tid] = 0.f;
  // per-thread constants
  float bahr = 0.f; float4 bias4 = {0, 0, 0, 0};
  if (tid < 512) {
    bahr = b_ah[j];
    bias4.x = bih_e[j] + bhh_e[j];
    bias4.y = bih_e[256 + j] + bhh_e[256 + j];
    bias4.z = bih_e[512 + j] + bhh_e[512 + j];
    bias4.w = bih_e[768 + j] + bhh_e[768 + j];
  }
  float ai0 = 0.f, ai1 = 0.f;
  {
    int m = tid & 127;
    if (m < MM) {
      ai0 = ws[OFF_ATTN + b0 * MM + m];
      ai1 = ws[OFF_ATTN + b1 * MM + m];
    }
  }
  const float bav = b_a[0];
  float xc0 = 0.f, xc1 = 0.f;
  if (tid < 128) {
    int bb = (tid >= 64) ? b1 : b0;
    int lane = tid & 63;
    xc0 = x[((size_t)bb * TT) * MM + lane];
    xc1 = (lane < 17) ? x[((size_t)bb * TT) * MM + 64 + lane] : 0.f;
  }
  const __half2* __restrict__ Wah2 = (const __half2*)(ws + OFF_W2AH);
  const uint4* __restrict__ We8 = (const uint4*)(ws + OFF_WE8);
  float4* __restrict__ arena4 = (float4*)arena;
  __syncthreads();

  for (int t = 0; t < TT; ++t) {
    // ---- p1: hid_proj partials (4-way k2 split) ----
    {
      float a0 = 0.f, a1 = 0.f;
      const int kb = q * 64;
      #pragma unroll 8
      for (int i = 0; i < 64; ++i) {
        int k2 = kb + i;
        float2 wf = __half22float2(Wah2[k2 * 256 + j]);
        float4 hv = *(const float4*)&hcat[k2 * 4];
        a0 = fmaf(wf.x, hv.x, fmaf(wf.y, hv.z, a0));
        a1 = fmaf(wf.x, hv.y, fmaf(wf.y, hv.w, a1));
      }
      arena[(q * 256 + j) * 2 + 0] = a0;
      arena[(q * 256 + j) * 2 + 1] = a1;
    }
    __syncthreads();
    if (tid < 512) {
      int b = tid >> 8, h = tid & 255;
      float v = arena[(0 * 256 + h) * 2 + b] + arena[(1 * 256 + h) * 2 + b] +
                arena[(2 * 256 + h) * 2 + b] + arena[(3 * 256 + h) * 2 + b] + bahr;
      hpb[2 * h + b] = v;
    }
    __syncthreads();
    // ---- p2: score[m] partials over 8 t-slices ----
    {
      int m = tid & 127, tq = tid >> 7;
      if (m < MM) {
        float e0 = 0.f, e1 = 0.f;
        #pragma unroll 8
        for (int i = tq * 16; i < tq * 16 + 16; ++i) {
          float4 hv = *(const float4*)&hpb[i * 4];
          float2 wv = *(const float2*)&wa2[i * 2];
          e0 += ftanh(hv.x + ai0) * wv.x + ftanh(hv.z + ai0) * wv.y;
          e1 += ftanh(hv.y + ai1) * wv.x + ftanh(hv.w + ai1) * wv.y;
        }
        arena[(tq * 2 + 0) * 96 + m] = e0;
        arena[(tq * 2 + 1) * 96 + m] = e1;
      }
    }
    __syncthreads();
    // ---- p3: softmax over m + wi (waves 0,1) ----
    if (tid < 128) {
      int wv_id = tid >> 6, lane = tid & 63;
      float v0 = bav, v1 = (lane < 17) ? bav : -1e30f;
      #pragma unroll
      for (int tq = 0; tq < 8; ++tq) {
        v0 += arena[(tq * 2 + wv_id) * 96 + lane];
        if (lane < 17) v1 += arena[(tq * 2 + wv_id) * 96 + 64 + lane];
      }
      float mx = fmaxf(v0, v1);
      #pragma unroll
      for (int d = 1; d < 64; d <<= 1) mx = fmaxf(mx, __shfl_xor(mx, d));
      float e0 = __expf(v0 - mx);
      float e1 = (lane < 17) ? __expf(v1 - mx) : 0.f;
      float sm = e0 + e1;
      #pragma unroll
      for (int d = 1; d < 64; d <<= 1) sm += __shfl_xor(sm, d);
      float inv = frcp(sm);
      float w0 = e0 * inv * xc0;
      float w1 = e1 * inv * xc1;
      int m0 = lane, m1 = 64 + lane;
      ubuf[(m0 >> 1) * 4 + (m0 & 1) * 2 + wv_id] = w0;
      if (lane < 17) ubuf[(m1 >> 1) * 4 + (m1 & 1) * 2 + wv_id] = w1;
      if (t < 255) {
        int bb = wv_id ? b1 : b0;
        xc0 = x[((size_t)bb * TT + t + 1) * MM + lane];
        xc1 = (lane < 17) ? x[((size_t)bb * TT + t + 1) * MM + 64 + lane] : 0.f;
      }
    }
    __syncthreads();
    // ---- p4: LSTM gate partials (4-way k2 split over 169) ----
    {
      const int kA = (q == 0) ? 0 : (q == 1) ? 43 : (q == 2) ? 86 : 128;
      const int kB = (q == 0) ? 43 : (q == 1) ? 86 : (q == 2) ? 128 : 169;
      float4 g0 = {0, 0, 0, 0}, g1 = {0, 0, 0, 0};
      #pragma unroll 4
      for (int k2 = kA; k2 < kB; ++k2) {
        uint4 wu = We8[k2 * 256 + j];
        float4 uv = *(const float4*)&ubuf[k2 * 4];
        gate_fma(wu, uv, g0, g1);
      }
      arena4[(q * 2 + 0) * 256 + j] = g0;
      arena4[(q * 2 + 1) * 256 + j] = g1;
    }
    __syncthreads();
    // ---- p4 reduce + state update ----
    if (tid < 512) {
      int b = tid >> 8, jj = tid & 255;
      float4 s0 = arena4[(0 * 2 + b) * 256 + jj];
      float4 s1 = arena4[(1 * 2 + b) * 256 + jj];
      float4 s2 = arena4[(2 * 2 + b) * 256 + jj];
      float4 s3 = arena4[(3 * 2 + b) * 256 + jj];
      float gi = s0.x + s1.x + s2.x + s3.x + bias4.x;
      float gf = s0.y + s1.y + s2.y + s3.y + bias4.y;
      float gg = s0.z + s1.z + s2.z + s3.z + bias4.z;
      float go = s0.w + s1.w + s2.w + s3.w + bias4.w;
      float cold = hcat[2 * (256 + jj) + b];
      float c = fsig(gf) * cold + fsig(gi) * ftanh(gg);
      float h = fsig(go) * ftanh(c);
      hcat[2 * jj + b] = h;
      hcat[2 * (256 + jj) + b] = c;
      int us = 81 + jj;
      ubuf[(us >> 1) * 4 + (us & 1) * 2 + b] = h;
      ws[OFF_ENC + (((size_t)(b ? b1 : b0) * TT + t) * HEE + jj)] = h;
    }
    __syncthreads();
  }
}

// ---------------- encW[b][t] = enc[b,t,:] . W_fc[:256] ----------------
__global__ __launch_bounds__(256) void k_encw(const float* __restrict__ W_fc, float* __restrict__ ws) {
  const float* __restrict__ enc = ws + OFF_ENC;
  const int wv = threadIdx.x >> 6, lane = threadIdx.x & 63;
  float4 wfc = reinterpret_cast<const float4*>(W_fc)[lane];
  for (int r = blockIdx.x * 4 + wv; r < BB * TT; r += 4096) {
    float4 e = reinterpret_cast<const float4*>(enc + (size_t)r * HEE)[lane];
    float d = e.x * wfc.x + e.y * wfc.y + e.z * wfc.z + e.w * wfc.w;
    #pragma unroll
    for (int dd = 1; dd < 64; dd <<= 1) d += __shfl_xor(d, dd);
    if (lane == 0) ws[OFF_ENCW + r] = d;
  }
}

// ---------------- enc_proj fp16: epH[b][t'][h] ----------------
__global__ __launch_bounds__(256) void k_encproj(const float* __restrict__ W_d1, float* __restrict__ ws) {
  __shared__ __align__(16) float le[16][256];
  const int tid = threadIdx.x;
  const int b = blockIdx.x >> 4;
  const int t0 = (blockIdx.x & 15) * 16;
  const float* __restrict__ enc = ws + OFF_ENC;
  __half* __restrict__ epH = (__half*)(ws + OFF_EPI);
  #pragma unroll
  for (int rr = 0; rr < 16; ++rr)
    le[rr][tid] = enc[((size_t)b * TT + (t0 + rr)) * HEE + tid];
  __syncthreads();
  const float4* wrow = (const float4*)(W_d1 + (size_t)tid * 768 + 512);
  float acc[16];
  #pragma unroll
  for (int r = 0; r < 16; ++r) acc[r] = 0.f;
  for (int e4 = 0; e4 < 64; ++e4) {
    float4 w = wrow[e4];
    #pragma unroll
    for (int r = 0; r < 16; ++r) {
      float4 ev = *(const float4*)&le[r][e4 * 4];
      acc[r] += ev.x * w.x + ev.y * w.y + ev.z * w.z + ev.w * w.w;
    }
  }
  #pragma unroll
  for (int rr = 0; rr < 16; ++rr)
    epH[((size_t)b * TT + (t0 + rr)) * HEE + tid] = __float2half(acc[rr]);
}

// ---------------- decoder: 1024 threads, 2 batch rows, 255 steps ----------------
__global__ __launch_bounds__(1024) __attribute__((amdgpu_waves_per_eu(4, 4))) void k_decoder(
    const float* __restrict__ y_history, const float* __restrict__ b_d1,
    const float* __restrict__ W_d2, const float* __restrict__ b_d2,
    const float* __restrict__ W_fc, const float* __restrict__ b_fc,
    const float* __restrict__ bih_d, const float* __restrict__ bhh_d,
    const float* __restrict__ W_ff, const float* __restrict__ b_ff,
    float* __restrict__ ws, float* __restrict__ out) {
  __shared__ __align__(16) ushort epL[65536];   // b0 enc_proj, swizzled, 128 KB
  __shared__ __align__(16) float arena[4096];   // pp / qp / gp / cp (16 KB)
  __shared__ __align__(16) float hcat[1024];    // [h;c] packed 2k+b
  __shared__ __align__(16) float ub2[2][260];   // per-batch LSTM input: [0]=y, [1+j]=h
  __shared__ __align__(16) float ddp2[512];     // d packed 2h+b
  __shared__ __align__(16) ushort w2h[256];     // W_d2 fp16
  __shared__ __align__(16) float ybuf[512];     // y*wfcy+bfc, 2s+b
  __shared__ __align__(16) float awls[512];     // last-step aw, 2t+b
  __shared__ float red[3][8];
  const int tid = threadIdx.x;
  const int tp = tid & 255, q = tid >> 8;
  const int lane = tid & 63, wvid = tid >> 6;
  const int b0 = blockIdx.x * 2, b1 = b0 + 1;

  const float wfcy = W_fc[256], bfc = b_fc[0], bd2v = b_d2[0];
  hcat[tid] = 0.f;
  if (tid < 520) ((float*)ub2)[tid] = 0.f;
  if (tid < 256) w2h[tid] = __half_as_ushort(__float2half(W_d2[tid]));
  if (tid < 510) {
    int s = tid >> 1, b = tid & 1;
    ybuf[tid] = y_history[(size_t)(b ? b1 : b0) * 255 + s] * wfcy + bfc;
  }
  float bd1r = 0.f; float4 biasd = {0, 0, 0, 0};
  if (tid < 512) {
    bd1r = b_d1[tp];
    biasd.x = bih_d[tp] + bhh_d[tp];
    biasd.y = bih_d[256 + tp] + bhh_d[256 + tp];
    biasd.z = bih_d[512 + tp] + bhh_d[512 + tp];
    biasd.w = bih_d[768 + tp] + bhh_d[768 + tp];
  }
  float ewr = 0.f;
  if (q < 2) ewr = ws[OFF_ENCW + (size_t)(q ? b1 : b0) * 256 + tp];

  // ---- load enc_proj: b0 -> swizzled LDS, b1 -> regs (pinned) ----
  const uint4* __restrict__ epg = (const uint4*)(ws + OFF_EPI);
  {
    const uint4* src = epg + (size_t)b0 * 8192;
    uint4* dst = (uint4*)epL;
    #pragma unroll
    for (int k = 0; k < 8; ++k) {
      int g = k * 1024 + tid;
      int t = g >> 5, c = g & 31;
      dst[(g & ~31) | (c ^ (t & 31))] = src[g];
    }
  }
  uint4 epr[8];
  {
    const uint4* s1 = epg + (size_t)b1 * 8192 + tp * 32 + q * 8;
    #pragma unroll
    for (int k = 0; k < 8; ++k) epr[k] = s1[k];
  }
  // pin epr in VGPRs: the empty asm "writes" the values, so the compiler can
  // neither rematerialize the global loads per-step nor sink them.
  #pragma unroll
  for (int k = 0; k < 8; ++k)
    asm volatile("" : "+v"(epr[k].x), "+v"(epr[k].y), "+v"(epr[k].z), "+v"(epr[k].w));

  const __half2* __restrict__ Wd2h = (const __half2*)(ws + OFF_W2D1);
  const uint4* __restrict__ Wd8 = (const uint4*)(ws + OFF_WD8);
  float4* __restrict__ arena4 = (float4*)arena;
  const uint4* __restrict__ ep16 = (const uint4*)epL;
  __syncthreads();

  for (int s = 0; s < 255; ++s) {
    // ---- p1: d = [h;c].W_d1hc^T partials ----
    {
      float a0 = 0.f, a1 = 0.f;
      const int kb = q * 64;
      #pragma unroll 8
      for (int i = 0; i < 64; ++i) {
        int k2 = kb + i;
        float2 wf = __half22float2(Wd2h[k2 * 256 + tp]);
        float4 hv = *(const float4*)&hcat[k2 * 4];
        a0 = fmaf(wf.x, hv.x, fmaf(wf.y, hv.z, a0));
        a1 = fmaf(wf.x, hv.y, fmaf(wf.y, hv.w, a1));
      }
      arena[(q * 256 + tp) * 2 + 0] = a0;
      arena[(q * 256 + tp) * 2 + 1] = a1;
    }
    __syncthreads();
    if (tid < 512) {
      int b = tid >> 8, h = tid & 255;
      float d = arena[(0 * 256 + h) * 2 + b] + arena[(1 * 256 + h) * 2 + b] +
                arena[(2 * 256 + h) * 2 + b] + arena[(3 * 256 + h) * 2 + b] + bd1r;
      ddp2[2 * h + b] = d;
    }
    __syncthreads();
    // ---- p2: score partials (b0 from LDS, b1 from regs) ----
    {
      float q0 = 0.f, q1 = 0.f;
      const int rowbase = tp * 32, sw = tp & 31;
      #pragma unroll
      for (int k = 0; k < 8; ++k) {
        uint4 e0u = ep16[rowbase + ((q * 8 + k) ^ sw)];
        uint4 e1u = epr[k];
        const int h8 = q * 64 + k * 8;
        uint4 w2u = *(const uint4*)&w2h[h8];
        const __half2* e0h = (const __half2*)&e0u;
        const __half2* e1h = (const __half2*)&e1u;
        const __half2* w2p = (const __half2*)&w2u;
        #pragma unroll
        for (int jj = 0; jj < 4; ++jj) {
          float2 ea = __half22float2(e0h[jj]);
          float2 eb = __half22float2(e1h[jj]);
          float2 wf = __half22float2(w2p[jj]);
          float4 dv = *(const float4*)&ddp2[2 * (h8 + 2 * jj)];
          q0 += wf.x * ftanh(ea.x + dv.x) + wf.y * ftanh(ea.y + dv.z);
          q1 += wf.x * ftanh(eb.x + dv.y) + wf.y * ftanh(eb.y + dv.w);
        }
      }
      arena[(q * 256 + tp) * 2 + 0] = q0;
      arena[(q * 256 + tp) * 2 + 1] = q1;
    }
    __syncthreads();
    // ---- p3: softmax over t' (q<2 active, b=q) ----
    float vsc = 0.f, esc = 0.f;
    if (q < 2) {
      vsc = arena[(0 * 256 + tp) * 2 + q] + arena[(1 * 256 + tp) * 2 + q] +
            arena[(2 * 256 + tp) * 2 + q] + arena[(3 * 256 + tp) * 2 + q] + bd2v;
      float mx = vsc;
      #pragma unroll
      for (int d = 1; d < 64; d <<= 1) mx = fmaxf(mx, __shfl_xor(mx, d));
      if (lane == 0) red[0][wvid] = mx;
    }
    __syncthreads();
    if (q < 2) {
      float mx = fmaxf(fmaxf(red[0][q * 4 + 0], red[0][q * 4 + 1]),
                       fmaxf(red[0][q * 4 + 2], red[0][q * 4 + 3]));
      esc = __expf(vsc - mx);
      float den = esc, num = esc * ewr;
      #pragma unroll
      for (int d = 1; d < 64; d <<= 1) { den += __shfl_xor(den, d); num += __shfl_xor(num, d); }
      if (lane == 0) { red[1][wvid] = den; red[2][wvid] = num; }
    }
    __syncthreads();
    if (q < 2) {
      float den = red[1][q * 4 + 0] + red[1][q * 4 + 1] + red[1][q * 4 + 2] + red[1][q * 4 + 3];
      float num = red[2][q * 4 + 0] + red[2][q * 4 + 1] + red[2][q * 4 + 2] + red[2][q * 4 + 3];
      float inv = frcp(den);
      if (tp == 0) ub2[q][0] = num * inv + ybuf[2 * s + q];
      if (s == 254) awls[2 * tp + q] = esc * inv;
    }
    __syncthreads();
    // ---- p5: decoder LSTM gate partials (per-batch, 2-way k2 split) ----
    {
      const int b = q >> 1, half = q & 1;
      const float* ub = ub2[b];
      const int kA = half ? 65 : 0, kB = half ? 129 : 65;
      float4 g = {0, 0, 0, 0};
      #pragma unroll 4
      for (int k2 = kA; k2 < kB; ++k2) {
        uint4 wu = Wd8[k2 * 256 + tp];
        const __half2* wh = (const __half2*)&wu;
        float2 ife = __half22float2(wh[0]);
        float2 goe = __half22float2(wh[1]);
        float2 ifo = __half22float2(wh[2]);
        float2 goo = __half22float2(wh[3]);
        float2 uv = *(const float2*)&ub[2 * k2];
        g.x = fmaf(ife.x, uv.x, fmaf(ifo.x, uv.y, g.x));
        g.y = fmaf(ife.y, uv.x, fmaf(ifo.y, uv.y, g.y));
        g.z = fmaf(goe.x, uv.x, fmaf(goo.x, uv.y, g.z));
        g.w = fmaf(goe.y, uv.x, fmaf(goo.y, uv.y, g.w));
      }
      arena4[q * 256 + tp] = g;
    }
    __syncthreads();
    if (tid < 512) {
      int b = tid >> 8, jj = tid & 255;
      float4 ga = arena4[(b * 2 + 0) * 256 + jj];
      float4 gb = arena4[(b * 2 + 1) * 256 + jj];
      float gi = ga.x + gb.x + biasd.x, gf = ga.y + gb.y + biasd.y;
      float gg = ga.z + gb.z + biasd.z, go = ga.w + gb.w + biasd.w;
      float cold = hcat[2 * (256 + jj) + b];
      float c = fsig(gf) * cold + fsig(gi) * ftanh(gg);
      float h = fsig(go) * ftanh(c);
      hcat[2 * jj + b] = h;
      hcat[2 * (256 + jj) + b] = c;
      ub2[b][1 + jj] = h;
    }
    __syncthreads();
  }

  // ---- final: ctx with last-step aw + output ----
  {
    float c0 = 0.f, c1 = 0.f;
    const float* __restrict__ e0p = ws + OFF_ENC + (size_t)b0 * TT * HEE;
    const float* __restrict__ e1p = ws + OFF_ENC + (size_t)b1 * TT * HEE;
    for (int t = q * 64; t < q * 64 + 64; ++t) {
      float2 aw = *(const float2*)&awls[2 * t];
      c0 = fmaf(aw.x, e0p[(size_t)t * HEE + tp], c0);
      c1 = fmaf(aw.y, e1p[(size_t)t * HEE + tp], c1);
    }
    arena[(q * 256 + tp) * 2 + 0] = c0;
    arena[(q * 256 + tp) * 2 + 1] = c1;
  }
  __syncthreads();
  if (tid < 512) {
    int b = tid >> 8, h = tid & 255;
    float ctx = arena[(0 * 256 + h) * 2 + b] + arena[(1 * 256 + h) * 2 + b] +
                arena[(2 * 256 + h) * 2 + b] + arena[(3 * 256 + h) * 2 + b];
    float hfin = hcat[2 * h + b];
    float p = hfin * W_ff[h] + ctx * W_ff[256 + h];
    #pragma unroll
    for (int d = 1; d < 64; d <<= 1) p += __shfl_xor(p, d);
    if (lane == 0) red[0][wvid] = p;
  }
  __syncthreads();
  if (tid == 0)   out[b0] = red[0][0] + red[0][1] + red[0][2] + red[0][3] + b_ff[0];
  if (tid == 256) out[b1] = red[0][4] + red[0][5] + red[0][6] + red[0][7] + b_ff[0];
}

extern "C" void kernel_launch(void* const* d_in, const int* in_sizes, int n_in,
                              void* d_out, int out_size, void* d_ws, size_t ws_size,
                              hipStream_t stream) {
  if (ws_size < (size_t)WS_FLOATS * sizeof(float)) return;
  const float* x     = (const float*)d_in[0];
  const float* y_h   = (const float*)d_in[1];
  const float* W_ah  = (const float*)d_in[2];
  const float* b_ah  = (const float*)d_in[3];
  const float* W_ai  = (const float*)d_in[4];
  const float* b_ai  = (const float*)d_in[5];
  const float* W_a   = (const float*)d_in[6];
  const float* b_a   = (const float*)d_in[7];
  const float* Wih_e = (const float*)d_in[8];
  const float* Whh_e = (const float*)d_in[9];
  const float* bih_e = (const float*)d_in[10];
  const float* bhh_e = (const float*)d_in[11];
  const float* W_d1  = (const float*)d_in[12];
  const float* b_d1  = (const float*)d_in[13];
  const float* W_d2  = (const float*)d_in[14];
  const float* b_d2  = (const float*)d_in[15];
  const float* W_fc  = (const float*)d_in[16];
  const float* b_fc  = (const float*)d_in[17];
  const float* Wih_d = (const float*)d_in[18];
  const float* Whh_d = (const float*)d_in[19];
  const float* bih_d = (const float*)d_in[20];
  const float* bhh_d = (const float*)d_in[21];
  const float* W_ff  = (const float*)d_in[22];
  const float* b_ff  = (const float*)d_in[23];
  float* ws  = (float*)d_ws;
  float* out = (float*)d_out;

  k_prep<<<256, 512, 0, stream>>>(W_ah, Wih_e, Whh_e, W_d1, Wih_d, Whh_d, ws);
  k_attn<<<512, 128, 0, stream>>>(x, W_ai, b_ai, ws);
  k_encoder<<<256, 1024, 0, stream>>>(x, b_ah, W_a, b_a, bih_e, bhh_e, ws);
  k_encw<<<1024, 256, 0, stream>>>(W_fc, ws);
  k_encproj<<<8192, 256, 0, stream>>>(W_d1, ws);
  k_decoder<<<256, 1024, 0, stream>>>(y_h, b_d1, W_d2, b_d2, W_fc, b_fc,
                                      bih_d, bhh_d, W_ff, b_ff, ws, out);
}

// Round 6
// 13366.428 us; speedup vs baseline: 1.6118x; 1.6118x over previous
//
#include <hip/hip_runtime.h>
#include <hip/hip_bf16.h>
#include <hip/hip_fp16.h>

#define BB  512
#define TT  256
#define MM  81
#define HEE 256

// ---- workspace layout (float offsets) ----
#define OFF_W2AH   0          // half2[256 k2][256 j]  encoder p1 weights
#define OFF_WE8    65536      // uint4[169 k2][256 j]  encoder LSTM weights (4 gates x k-pair, fp16)
#define OFF_W4D1   238592     // uint2[128 k4][256 j]  decoder p1 weights (4 halves: k=4k4..4k4+3)
#define OFF_WD8    304128     // uint4[129 k2][256 j]  decoder LSTM weights
#define OFF_ATTN   436224     // [512][81] attn_in
#define OFF_ENCW   477696     // [512][256] enc . W_fc[:256]
#define OFF_ENC    608768     // [512][256][256] input_encoded fp32
#define OFF_EPI    34163200   // half[512 b][256 t'][256 h] enc_proj
#define WS_FLOATS  50940416

__device__ __forceinline__ float frcp(float x) { return __builtin_amdgcn_rcpf(x); }
__device__ __forceinline__ float fsig(float x) { return frcp(1.f + __expf(-x)); }
__device__ __forceinline__ float ftanh(float x) { return 1.f - 2.f * frcp(__expf(2.f * x) + 1.f); }

// both-batch gate FMA (encoder): uv = (u[ke]b0, u[ke]b1, u[ko]b0, u[ko]b1)
__device__ __forceinline__ void gate_fma(const uint4& wu, const float4& uv, float4& g0, float4& g1) {
  const __half2* wh = reinterpret_cast<const __half2*>(&wu);
  float2 if0 = __half22float2(wh[0]);
  float2 go0 = __half22float2(wh[1]);
  float2 if1 = __half22float2(wh[2]);
  float2 go1 = __half22float2(wh[3]);
  g0.x = fmaf(if0.x, uv.x, fmaf(if1.x, uv.z, g0.x));
  g0.y = fmaf(if0.y, uv.x, fmaf(if1.y, uv.z, g0.y));
  g0.z = fmaf(go0.x, uv.x, fmaf(go1.x, uv.z, g0.z));
  g0.w = fmaf(go0.y, uv.x, fmaf(go1.y, uv.z, g0.w));
  g1.x = fmaf(if0.x, uv.y, fmaf(if1.x, uv.w, g1.x));
  g1.y = fmaf(if0.y, uv.y, fmaf(if1.y, uv.w, g1.y));
  g1.z = fmaf(go0.x, uv.y, fmaf(go1.x, uv.w, g1.z));
  g1.w = fmaf(go0.y, uv.y, fmaf(go1.y, uv.w, g1.w));
}

// ---------------- weight prep ----------------
__global__ void k_prep(const float* __restrict__ W_ah, const float* __restrict__ Wih_e,
                       const float* __restrict__ Whh_e, const float* __restrict__ W_d1,
                       const float* __restrict__ Wih_d, const float* __restrict__ Whh_d,
                       float* __restrict__ ws) {
  int idx = blockIdx.x * 512 + threadIdx.x;
  if (idx < 65536) {
    int k2 = idx >> 8, j = idx & 255;
    ((__half2*)(ws + OFF_W2AH))[idx] =
        __floats2half2_rn(W_ah[j * 512 + 2 * k2], W_ah[j * 512 + 2 * k2 + 1]);
  }
  if (idx < 32768) {  // decoder p1: uint2[k4][j], 4 halves per elem
    int k4 = idx >> 8, j = idx & 255;
    __half2 a = __floats2half2_rn(W_d1[j * 768 + 4 * k4 + 0], W_d1[j * 768 + 4 * k4 + 1]);
    __half2 b = __floats2half2_rn(W_d1[j * 768 + 4 * k4 + 2], W_d1[j * 768 + 4 * k4 + 3]);
    uint2 w;
    w.x = *(const unsigned int*)&a;
    w.y = *(const unsigned int*)&b;
    ((uint2*)(ws + OFF_W4D1))[idx] = w;
  }
  if (idx < 43264) {  // 169*256
    int k2 = idx >> 8, j = idx & 255;
    auto we = [&](int g, int kk) -> float {
      if (kk < 81)  return Wih_e[(g * 256 + j) * 81 + kk];
      if (kk < 337) return Whh_e[(g * 256 + j) * 256 + (kk - 81)];
      return 0.f;
    };
    int ke = 2 * k2, ko = 2 * k2 + 1;
    union { __half2 h[4]; uint4 u; } w;
    w.h[0] = __floats2half2_rn(we(0, ke), we(1, ke));
    w.h[1] = __floats2half2_rn(we(2, ke), we(3, ke));
    w.h[2] = __floats2half2_rn(we(0, ko), we(1, ko));
    w.h[3] = __floats2half2_rn(we(2, ko), we(3, ko));
    ((uint4*)(ws + OFF_WE8))[idx] = w.u;
  }
  if (idx < 33024) {  // 129*256
    int k2 = idx >> 8, j = idx & 255;
    auto wd = [&](int g, int kk) -> float {
      if (kk == 0)  return Wih_d[g * 256 + j];
      if (kk < 257) return Whh_d[(g * 256 + j) * 256 + (kk - 1)];
      return 0.f;
    };
    int ke = 2 * k2, ko = 2 * k2 + 1;
    union { __half2 h[4]; uint4 u; } w;
    w.h[0] = __floats2half2_rn(wd(0, ke), wd(1, ke));
    w.h[1] = __floats2half2_rn(wd(2, ke), wd(3, ke));
    w.h[2] = __floats2half2_rn(wd(0, ko), wd(1, ko));
    w.h[3] = __floats2half2_rn(wd(2, ko), wd(3, ko));
    ((uint4*)(ws + OFF_WD8))[idx] = w.u;
  }
}

// ---------------- attn_in[b][m] ----------------
__global__ void k_attn(const float* __restrict__ x, const float* __restrict__ W_ai,
                       const float* __restrict__ b_ai, float* __restrict__ ws) {
  __shared__ float wai[256];
  const int b = blockIdx.x, tid = threadIdx.x;  // 128 threads
  wai[tid] = W_ai[tid];
  wai[128 + tid] = W_ai[128 + tid];
  __syncthreads();
  if (tid < MM) {
    float acc = b_ai[0];
    const float* xp = x + (size_t)b * TT * MM + tid;
    #pragma unroll 8
    for (int t = 0; t < TT; ++t) acc = fmaf(xp[t * MM], wai[t], acc);
    ws[OFF_ATTN + b * MM + tid] = acc;
  }
}

// ---------------- encoder: 1024 threads, 2 batch rows, 256 steps (unchanged from R5) ----------------
__global__ __launch_bounds__(1024, 2) void k_encoder(
    const float* __restrict__ x, const float* __restrict__ b_ah,
    const float* __restrict__ W_a, const float* __restrict__ b_a,
    const float* __restrict__ bih_e, const float* __restrict__ bhh_e,
    float* __restrict__ ws) {
  __shared__ __align__(16) float arena[8192];
  __shared__ __align__(16) float hcat[1024];
  __shared__ __align__(16) float ubuf[680];
  __shared__ __align__(16) float hpb[512];
  __shared__ __align__(16) float wa2[256];
  const int tid = threadIdx.x;
  const int j = tid & 255, q = tid >> 8;
  const int b0 = blockIdx.x * 2, b1 = b0 + 1;

  if (tid < 256) wa2[tid] = W_a[tid];
  hcat[tid] = 0.f;
  if (tid < 680) ubuf[tid] = 0.f;
  float bahr = 0.f; float4 bias4 = {0, 0, 0, 0};
  if (tid < 512) {
    bahr = b_ah[j];
    bias4.x = bih_e[j] + bhh_e[j];
    bias4.y = bih_e[256 + j] + bhh_e[256 + j];
    bias4.z = bih_e[512 + j] + bhh_e[512 + j];
    bias4.w = bih_e[768 + j] + bhh_e[768 + j];
  }
  float ai0 = 0.f, ai1 = 0.f;
  {
    int m = tid & 127;
    if (m < MM) {
      ai0 = ws[OFF_ATTN + b0 * MM + m];
      ai1 = ws[OFF_ATTN + b1 * MM + m];
    }
  }
  const float bav = b_a[0];
  float xc0 = 0.f, xc1 = 0.f;
  if (tid < 128) {
    int bb = (tid >= 64) ? b1 : b0;
    int lane = tid & 63;
    xc0 = x[((size_t)bb * TT) * MM + lane];
    xc1 = (lane < 17) ? x[((size_t)bb * TT) * MM + 64 + lane] : 0.f;
  }
  const __half2* __restrict__ Wah2 = (const __half2*)(ws + OFF_W2AH);
  const uint4* __restrict__ We8 = (const uint4*)(ws + OFF_WE8);
  float4* __restrict__ arena4 = (float4*)arena;
  __syncthreads();

  for (int t = 0; t < TT; ++t) {
    {
      float a0 = 0.f, a1 = 0.f;
      const int kb = q * 64;
      #pragma unroll 8
      for (int i = 0; i < 64; ++i) {
        int k2 = kb + i;
        float2 wf = __half22float2(Wah2[k2 * 256 + j]);
        float4 hv = *(const float4*)&hcat[k2 * 4];
        a0 = fmaf(wf.x, hv.x, fmaf(wf.y, hv.z, a0));
        a1 = fmaf(wf.x, hv.y, fmaf(wf.y, hv.w, a1));
      }
      arena[(q * 256 + j) * 2 + 0] = a0;
      arena[(q * 256 + j) * 2 + 1] = a1;
    }
    __syncthreads();
    if (tid < 512) {
      int b = tid >> 8, h = tid & 255;
      float v = arena[(0 * 256 + h) * 2 + b] + arena[(1 * 256 + h) * 2 + b] +
                arena[(2 * 256 + h) * 2 + b] + arena[(3 * 256 + h) * 2 + b] + bahr;
      hpb[2 * h + b] = v;
    }
    __syncthreads();
    {
      int m = tid & 127, tq = tid >> 7;
      if (m < MM) {
        float e0 = 0.f, e1 = 0.f;
        #pragma unroll 8
        for (int i = tq * 16; i < tq * 16 + 16; ++i) {
          float4 hv = *(const float4*)&hpb[i * 4];
          float2 wv = *(const float2*)&wa2[i * 2];
          e0 += ftanh(hv.x + ai0) * wv.x + ftanh(hv.z + ai0) * wv.y;
          e1 += ftanh(hv.y + ai1) * wv.x + ftanh(hv.w + ai1) * wv.y;
        }
        arena[(tq * 2 + 0) * 96 + m] = e0;
        arena[(tq * 2 + 1) * 96 + m] = e1;
      }
    }
    __syncthreads();
    if (tid < 128) {
      int wv_id = tid >> 6, lane = tid & 63;
      float v0 = bav, v1 = (lane < 17) ? bav : -1e30f;
      #pragma unroll
      for (int tq = 0; tq < 8; ++tq) {
        v0 += arena[(tq * 2 + wv_id) * 96 + lane];
        if (lane < 17) v1 += arena[(tq * 2 + wv_id) * 96 + 64 + lane];
      }
      float mx = fmaxf(v0, v1);
      #pragma unroll
      for (int d = 1; d < 64; d <<= 1) mx = fmaxf(mx, __shfl_xor(mx, d));
      float e0 = __expf(v0 - mx);
      float e1 = (lane < 17) ? __expf(v1 - mx) : 0.f;
      float sm = e0 + e1;
      #pragma unroll
      for (int d = 1; d < 64; d <<= 1) sm += __shfl_xor(sm, d);
      float inv = frcp(sm);
      float w0 = e0 * inv * xc0;
      float w1 = e1 * inv * xc1;
      int m0 = lane, m1 = 64 + lane;
      ubuf[(m0 >> 1) * 4 + (m0 & 1) * 2 + wv_id] = w0;
      if (lane < 17) ubuf[(m1 >> 1) * 4 + (m1 & 1) * 2 + wv_id] = w1;
      if (t < 255) {
        int bb = wv_id ? b1 : b0;
        xc0 = x[((size_t)bb * TT + t + 1) * MM + lane];
        xc1 = (lane < 17) ? x[((size_t)bb * TT + t + 1) * MM + 64 + lane] : 0.f;
      }
    }
    __syncthreads();
    {
      const int kA = (q == 0) ? 0 : (q == 1) ? 43 : (q == 2) ? 86 : 128;
      const int kB = (q == 0) ? 43 : (q == 1) ? 86 : (q == 2) ? 128 : 169;
      float4 g0 = {0, 0, 0, 0}, g1 = {0, 0, 0, 0};
      #pragma unroll 4
      for (int k2 = kA; k2 < kB; ++k2) {
        uint4 wu = We8[k2 * 256 + j];
        float4 uv = *(const float4*)&ubuf[k2 * 4];
        gate_fma(wu, uv, g0, g1);
      }
      arena4[(q * 2 + 0) * 256 + j] = g0;
      arena4[(q * 2 + 1) * 256 + j] = g1;
    }
    __syncthreads();
    if (tid < 512) {
      int b = tid >> 8, jj = tid & 255;
      float4 s0 = arena4[(0 * 2 + b) * 256 + jj];
      float4 s1 = arena4[(1 * 2 + b) * 256 + jj];
      float4 s2 = arena4[(2 * 2 + b) * 256 + jj];
      float4 s3 = arena4[(3 * 2 + b) * 256 + jj];
      float gi = s0.x + s1.x + s2.x + s3.x + bias4.x;
      float gf = s0.y + s1.y + s2.y + s3.y + bias4.y;
      float gg = s0.z + s1.z + s2.z + s3.z + bias4.z;
      float go = s0.w + s1.w + s2.w + s3.w + bias4.w;
      float cold = hcat[2 * (256 + jj) + b];
      float c = fsig(gf) * cold + fsig(gi) * ftanh(gg);
      float h = fsig(go) * ftanh(c);
      hcat[2 * jj + b] = h;
      hcat[2 * (256 + jj) + b] = c;
      int us = 81 + jj;
      ubuf[(us >> 1) * 4 + (us & 1) * 2 + b] = h;
      ws[OFF_ENC + (((size_t)(b ? b1 : b0) * TT + t) * HEE + jj)] = h;
    }
    __syncthreads();
  }
}

// ---------------- encW[b][t] = enc[b,t,:] . W_fc[:256] ----------------
__global__ __launch_bounds__(256) void k_encw(const float* __restrict__ W_fc, float* __restrict__ ws) {
  const float* __restrict__ enc = ws + OFF_ENC;
  const int wv = threadIdx.x >> 6, lane = threadIdx.x & 63;
  float4 wfc = reinterpret_cast<const float4*>(W_fc)[lane];
  for (int r = blockIdx.x * 4 + wv; r < BB * TT; r += 4096) {
    float4 e = reinterpret_cast<const float4*>(enc + (size_t)r * HEE)[lane];
    float d = e.x * wfc.x + e.y * wfc.y + e.z * wfc.z + e.w * wfc.w;
    #pragma unroll
    for (int dd = 1; dd < 64; dd <<= 1) d += __shfl_xor(d, dd);
    if (lane == 0) ws[OFF_ENCW + r] = d;
  }
}

// ---------------- enc_proj fp16: epH[b][t'][h] ----------------
__global__ __launch_bounds__(256) void k_encproj(const float* __restrict__ W_d1, float* __restrict__ ws) {
  __shared__ __align__(16) float le[16][256];
  const int tid = threadIdx.x;
  const int b = blockIdx.x >> 4;
  const int t0 = (blockIdx.x & 15) * 16;
  const float* __restrict__ enc = ws + OFF_ENC;
  __half* __restrict__ epH = (__half*)(ws + OFF_EPI);
  #pragma unroll
  for (int rr = 0; rr < 16; ++rr)
    le[rr][tid] = enc[((size_t)b * TT + (t0 + rr)) * HEE + tid];
  __syncthreads();
  const float4* wrow = (const float4*)(W_d1 + (size_t)tid * 768 + 512);
  float acc[16];
  #pragma unroll
  for (int r = 0; r < 16; ++r) acc[r] = 0.f;
  for (int e4 = 0; e4 < 64; ++e4) {
    float4 w = wrow[e4];
    #pragma unroll
    for (int r = 0; r < 16; ++r) {
      float4 ev = *(const float4*)&le[r][e4 * 4];
      acc[r] += ev.x * w.x + ev.y * w.y + ev.z * w.z + ev.w * w.w;
    }
  }
  #pragma unroll
  for (int rr = 0; rr < 16; ++rr)
    epH[((size_t)b * TT + (t0 + rr)) * HEE + tid] = __float2half(acc[rr]);
}

// ---------------- decoder: 1024 threads, 1 batch at a time (2 sequential passes), 255 steps ----------------
__global__ __launch_bounds__(1024) void k_decoder(
    const float* __restrict__ y_history, const float* __restrict__ b_d1,
    const float* __restrict__ W_d2, const float* __restrict__ b_d2,
    const float* __restrict__ W_fc, const float* __restrict__ b_fc,
    const float* __restrict__ bih_d, const float* __restrict__ bhh_d,
    const float* __restrict__ W_ff, const float* __restrict__ b_ff,
    float* __restrict__ ws, float* __restrict__ out) {
  __shared__ __align__(16) ushort epL[65536];   // current batch enc_proj, swizzled, 128 KB
  __shared__ __align__(16) float arena[4096];   // partials (16 KB, reused by all phases)
  __shared__ __align__(16) float hcat[512];     // [h(256); c(256)]
  __shared__ __align__(16) float ubf[260];      // LSTM input u: [0]=y, [1..256]=h, pad
  __shared__ __align__(16) float ddp[256];      // d vector
  __shared__ __align__(16) ushort w2h[256];     // W_d2 fp16
  __shared__ __align__(16) float ybuf[256];     // y*wfcy+bfc per step
  __shared__ __align__(16) float awls[256];     // last-step attention weights
  __shared__ float red[3][4];
  const int tid = threadIdx.x;
  const int tp = tid & 255, q = tid >> 8;
  const int lane = tid & 63, wvid = tid >> 6;   // for tid<256: wvid in 0..3
  const float wfcy = W_fc[256], bfc = b_fc[0], bd2v = b_d2[0];

  if (tid < 256) w2h[tid] = __half_as_ushort(__float2half(W_d2[tid]));
  float bd1r = 0.f; float4 biasd = {0, 0, 0, 0}; float wffh = 0.f, wffc = 0.f;
  if (tid < 256) {
    bd1r = b_d1[tp];
    biasd.x = bih_d[tp] + bhh_d[tp];
    biasd.y = bih_d[256 + tp] + bhh_d[256 + tp];
    biasd.z = bih_d[512 + tp] + bhh_d[512 + tp];
    biasd.w = bih_d[768 + tp] + bhh_d[768 + tp];
    wffh = W_ff[tp]; wffc = W_ff[256 + tp];
  }
  const uint2* __restrict__ W4 = (const uint2*)(ws + OFF_W4D1);
  const uint4* __restrict__ Wd8 = (const uint4*)(ws + OFF_WD8);
  const uint4* __restrict__ epg = (const uint4*)(ws + OFF_EPI);
  float4* __restrict__ arena4 = (float4*)arena;
  const uint4* __restrict__ ep16 = (const uint4*)epL;
  const int kA = (q == 0) ? 0 : (q == 1) ? 33 : (q == 2) ? 65 : 97;
  const int kB = (q == 0) ? 33 : (q == 1) ? 65 : (q == 2) ? 97 : 129;

  for (int bp = 0; bp < 2; ++bp) {
    const int b = blockIdx.x * 2 + bp;
    // ---- per-pass init ----
    if (tid < 512) hcat[tid] = 0.f;
    if (tid < 260) ubf[tid] = 0.f;
    if (tid < 255) ybuf[tid] = y_history[(size_t)b * 255 + tid] * wfcy + bfc;
    float ewr = (tid < 256) ? ws[OFF_ENCW + (size_t)b * 256 + tp] : 0.f;
    {
      const uint4* src = epg + (size_t)b * 8192;
      #pragma unroll
      for (int k = 0; k < 8; ++k) {
        int g = k * 1024 + tid;
        int t = g >> 5, c = g & 31;
        ((uint4*)epL)[(g & ~31) | (c ^ (t & 31))] = src[g];
      }
    }
    __syncthreads();

    for (int s = 0; s < 255; ++s) {
      // ---- p1: d = [h;c].W_d1hc^T partials (4-way k split, 8B weight loads) ----
      {
        float a0 = 0.f;
        const int k4b = q * 32;
        #pragma unroll 8
        for (int i = 0; i < 32; ++i) {
          int k4 = k4b + i;
          uint2 wu = W4[k4 * 256 + tp];
          float2 wA = __half22float2(*(const __half2*)&wu.x);
          float2 wB = __half22float2(*(const __half2*)&wu.y);
          float4 hv = *(const float4*)&hcat[4 * k4];
          a0 = fmaf(wA.x, hv.x, fmaf(wA.y, hv.y, fmaf(wB.x, hv.z, fmaf(wB.y, hv.w, a0))));
        }
        arena[q * 256 + tp] = a0;
      }
      __syncthreads();
      if (tid < 256)
        ddp[tid] = arena[tid] + arena[256 + tid] + arena[512 + tid] + arena[768 + tid] + bd1r;
      __syncthreads();
      // ---- p2: score[t'] partials from LDS enc_proj ----
      {
        float q0 = 0.f;
        const int rowbase = tp * 32, sw = tp & 31;
        #pragma unroll
        for (int k = 0; k < 8; ++k) {
          uint4 e0u = ep16[rowbase + ((q * 8 + k) ^ sw)];
          const int h8 = q * 64 + k * 8;
          uint4 w2u = *(const uint4*)&w2h[h8];
          float4 dva = *(const float4*)&ddp[h8];
          float4 dvb = *(const float4*)&ddp[h8 + 4];
          const __half2* e0h = (const __half2*)&e0u;
          const __half2* w2p = (const __half2*)&w2u;
          float2 ea, wf;
          ea = __half22float2(e0h[0]); wf = __half22float2(w2p[0]);
          q0 += wf.x * ftanh(ea.x + dva.x) + wf.y * ftanh(ea.y + dva.y);
          ea = __half22float2(e0h[1]); wf = __half22float2(w2p[1]);
          q0 += wf.x * ftanh(ea.x + dva.z) + wf.y * ftanh(ea.y + dva.w);
          ea = __half22float2(e0h[2]); wf = __half22float2(w2p[2]);
          q0 += wf.x * ftanh(ea.x + dvb.x) + wf.y * ftanh(ea.y + dvb.y);
          ea = __half22float2(e0h[3]); wf = __half22float2(w2p[3]);
          q0 += wf.x * ftanh(ea.x + dvb.z) + wf.y * ftanh(ea.y + dvb.w);
        }
        arena[q * 256 + tp] = q0;
      }
      __syncthreads();
      // ---- p3: softmax over t' ----
      float vsc = 0.f, esc = 0.f;
      if (tid < 256) {
        vsc = arena[tid] + arena[256 + tid] + arena[512 + tid] + arena[768 + tid] + bd2v;
        float mx = vsc;
        #pragma unroll
        for (int d = 1; d < 64; d <<= 1) mx = fmaxf(mx, __shfl_xor(mx, d));
        if (lane == 0) red[0][wvid] = mx;
      }
      __syncthreads();
      if (tid < 256) {
        float mx = fmaxf(fmaxf(red[0][0], red[0][1]), fmaxf(red[0][2], red[0][3]));
        esc = __expf(vsc - mx);
        float den = esc, num = esc * ewr;
        #pragma unroll
        for (int d = 1; d < 64; d <<= 1) { den += __shfl_xor(den, d); num += __shfl_xor(num, d); }
        if (lane == 0) { red[1][wvid] = den; red[2][wvid] = num; }
      }
      __syncthreads();
      if (tid < 256) {
        float den = red[1][0] + red[1][1] + red[1][2] + red[1][3];
        float num = red[2][0] + red[2][1] + red[2][2] + red[2][3];
        float inv = frcp(den);
        if (tid == 0) ubf[0] = num * inv + ybuf[s];
        if (s == 254) awls[tid] = esc * inv;
      }
      __syncthreads();
      // ---- p5: LSTM gate partials (4-way k split over 129 k-pairs) ----
      {
        float4 g = {0, 0, 0, 0};
        #pragma unroll 4
        for (int k2 = kA; k2 < kB; ++k2) {
          uint4 wu = Wd8[k2 * 256 + tp];
          const __half2* wh = (const __half2*)&wu;
          float2 ife = __half22float2(wh[0]);
          float2 goe = __half22float2(wh[1]);
          float2 ifo = __half22float2(wh[2]);
          float2 goo = __half22float2(wh[3]);
          float2 uv = *(const float2*)&ubf[2 * k2];
          g.x = fmaf(ife.x, uv.x, fmaf(ifo.x, uv.y, g.x));
          g.y = fmaf(ife.y, uv.x, fmaf(ifo.y, uv.y, g.y));
          g.z = fmaf(goe.x, uv.x, fmaf(goo.x, uv.y, g.z));
          g.w = fmaf(goe.y, uv.x, fmaf(goo.y, uv.y, g.w));
        }
        arena4[q * 256 + tp] = g;
      }
      __syncthreads();
      if (tid < 256) {
        float4 s0 = arena4[tid], s1 = arena4[256 + tid];
        float4 s2 = arena4[512 + tid], s3 = arena4[768 + tid];
        float gi = s0.x + s1.x + s2.x + s3.x + biasd.x;
        float gf = s0.y + s1.y + s2.y + s3.y + biasd.y;
        float gg = s0.z + s1.z + s2.z + s3.z + biasd.z;
        float go = s0.w + s1.w + s2.w + s3.w + biasd.w;
        float cold = hcat[256 + tid];
        float c = fsig(gf) * cold + fsig(gi) * ftanh(gg);
        float h = fsig(go) * ftanh(c);
        hcat[tid] = h;
        hcat[256 + tid] = c;
        ubf[1 + tid] = h;
      }
      __syncthreads();
    }

    // ---- finale for batch b: ctx with last-step aw + output ----
    {
      float c0 = 0.f;
      const float* __restrict__ ep = ws + OFF_ENC + (size_t)b * TT * HEE;
      for (int t = q * 64; t < q * 64 + 64; ++t)
        c0 = fmaf(awls[t], ep[(size_t)t * HEE + tp], c0);
      arena[q * 256 + tp] = c0;
    }
    __syncthreads();
    if (tid < 256) {
      float ctx = arena[tid] + arena[256 + tid] + arena[512 + tid] + arena[768 + tid];
      float p = hcat[tid] * wffh + ctx * wffc;
      #pragma unroll
      for (int d = 1; d < 64; d <<= 1) p += __shfl_xor(p, d);
      if (lane == 0) red[0][wvid] = p;
    }
    __syncthreads();
    if (tid == 0) out[b] = red[0][0] + red[0][1] + red[0][2] + red[0][3] + b_ff[0];
    __syncthreads();  // protect state before next pass re-init
  }
}

extern "C" void kernel_launch(void* const* d_in, const int* in_sizes, int n_in,
                              void* d_out, int out_size, void* d_ws, size_t ws_size,
                              hipStream_t stream) {
  if (ws_size < (size_t)WS_FLOATS * sizeof(float)) return;
  const float* x     = (const float*)d_in[0];
  const float* y_h   = (const float*)d_in[1];
  const float* W_ah  = (const float*)d_in[2];
  const float* b_ah  = (const float*)d_in[3];
  const float* W_ai  = (const float*)d_in[4];
  const float* b_ai  = (const float*)d_in[5];
  const float* W_a   = (const float*)d_in[6];
  const float* b_a   = (const float*)d_in[7];
  const float* Wih_e = (const float*)d_in[8];
  const float* Whh_e = (const float*)d_in[9];
  const float* bih_e = (const float*)d_in[10];
  const float* bhh_e = (const float*)d_in[11];
  const float* W_d1  = (const float*)d_in[12];
  const float* b_d1  = (const float*)d_in[13];
  const float* W_d2  = (const float*)d_in[14];
  const float* b_d2  = (const float*)d_in[15];
  const float* W_fc  = (const float*)d_in[16];
  const float* b_fc  = (const float*)d_in[17];
  const float* Wih_d = (const float*)d_in[18];
  const float* Whh_d = (const float*)d_in[19];
  const float* bih_d = (const float*)d_in[20];
  const float* bhh_d = (const float*)d_in[21];
  const float* W_ff  = (const float*)d_in[22];
  const float* b_ff  = (const float*)d_in[23];
  float* ws  = (float*)d_ws;
  float* out = (float*)d_out;

  k_prep<<<256, 512, 0, stream>>>(W_ah, Wih_e, Whh_e, W_d1, Wih_d, Whh_d, ws);
  k_attn<<<512, 128, 0, stream>>>(x, W_ai, b_ai, ws);
  k_encoder<<<256, 1024, 0, stream>>>(x, b_ah, W_a, b_a, bih_e, bhh_e, ws);
  k_encw<<<1024, 256, 0, stream>>>(W_fc, ws);
  k_encproj<<<8192, 256, 0, stream>>>(W_d1, ws);
  k_decoder<<<256, 1024, 0, stream>>>(y_h, b_d1, W_d2, b_d2, W_fc, b_fc,
                                      bih_d, bhh_d, W_ff, b_ff, ws, out);
}

// Round 8
// 12163.560 us; speedup vs baseline: 1.7712x; 1.0989x over previous
//
#include <hip/hip_runtime.h>
#include <hip/hip_bf16.h>
#include <hip/hip_fp16.h>

#define BB  512
#define TT  256
#define MM  81
#define HEE 256

// ---- workspace layout (float offsets) ----
#define OFF_W2AH   0          // half2[256 k2][256 j]  encoder p1 weight pairs (W_ah[j][2k2],[2k2+1])
#define OFF_WE8    65536      // uint4[169 k2][256 j]  encoder LSTM, gate-major pairs (i,f,g,o)
#define OFF_W4D1   238592     // uint2[128 k4][256 j]  decoder p1 pairs (k=4k4..4k4+3)
#define OFF_WD8    304128     // uint4[128 k2][256 j]  decoder Whh, gate-major pairs
#define OFF_ATTN   436224     // [512][81] attn_in
#define OFF_ENCW   477696     // [512][256] enc . W_fc[:256]
#define OFF_ENC    608768     // [512][256][256] input_encoded fp32
#define OFF_EPI    34163200   // half[512 b][256 t'][256 h] enc_proj
#define WS_FLOATS  50940416

typedef _Float16 hh2 __attribute__((ext_vector_type(2)));

__device__ __forceinline__ float frcp(float x) { return __builtin_amdgcn_rcpf(x); }
__device__ __forceinline__ float fsig(float x) { return frcp(1.f + __expf(-x)); }
__device__ __forceinline__ float ftanh(float x) { return 1.f - 2.f * frcp(__expf(2.f * x) + 1.f); }
__device__ __forceinline__ hh2 uash2(unsigned int u) { union { unsigned int u; hh2 h; } x; x.u = u; return x.h; }
__device__ __forceinline__ float fdot2f(unsigned int a, unsigned int b, float c) {
#if __has_builtin(__builtin_amdgcn_fdot2)
  return __builtin_amdgcn_fdot2(uash2(a), uash2(b), c, false);
#else
  hh2 ha = uash2(a), hb = uash2(b);
  return c + (float)ha.x * (float)hb.x + (float)ha.y * (float)hb.y;
#endif
}
__device__ __forceinline__ ushort f2h(float x) { return __half_as_ushort(__float2half(x)); }

// ---------------- weight prep ----------------
__global__ void k_prep(const float* __restrict__ W_ah, const float* __restrict__ Wih_e,
                       const float* __restrict__ Whh_e, const float* __restrict__ W_d1,
                       const float* __restrict__ Wih_d, const float* __restrict__ Whh_d,
                       float* __restrict__ ws) {
  int idx = blockIdx.x * 512 + threadIdx.x;
  if (idx < 65536) {  // encoder p1 pairs
    int k2 = idx >> 8, j = idx & 255;
    ((__half2*)(ws + OFF_W2AH))[idx] =
        __floats2half2_rn(W_ah[j * 512 + 2 * k2], W_ah[j * 512 + 2 * k2 + 1]);
  }
  if (idx < 32768) {  // decoder p1 pairs
    int k4 = idx >> 8, j = idx & 255;
    __half2 a = __floats2half2_rn(W_d1[j * 768 + 4 * k4 + 0], W_d1[j * 768 + 4 * k4 + 1]);
    __half2 b = __floats2half2_rn(W_d1[j * 768 + 4 * k4 + 2], W_d1[j * 768 + 4 * k4 + 3]);
    uint2 w;
    w.x = *(const unsigned int*)&a;
    w.y = *(const unsigned int*)&b;
    ((uint2*)(ws + OFF_W4D1))[idx] = w;
  }
  if (idx < 43264) {  // encoder LSTM: gate-major pairs over u=[wi(81);h(256);pad]
    int k2 = idx >> 8, j = idx & 255;
    auto we = [&](int g, int kk) -> float {
      if (kk < 81)  return Wih_e[(g * 256 + j) * 81 + kk];
      if (kk < 337) return Whh_e[(g * 256 + j) * 256 + (kk - 81)];
      return 0.f;
    };
    int ke = 2 * k2, ko = 2 * k2 + 1;
    union { __half2 h[4]; uint4 u; } w;
    w.h[0] = __floats2half2_rn(we(0, ke), we(0, ko));
    w.h[1] = __floats2half2_rn(we(1, ke), we(1, ko));
    w.h[2] = __floats2half2_rn(we(2, ke), we(2, ko));
    w.h[3] = __floats2half2_rn(we(3, ke), we(3, ko));
    ((uint4*)(ws + OFF_WE8))[idx] = w.u;
  }
  if (idx < 32768) {  // decoder Whh: gate-major pairs, 128 k2
    int k2 = idx >> 8, j = idx & 255;
    int ke = 2 * k2, ko = 2 * k2 + 1;
    union { __half2 h[4]; uint4 u; } w;
    w.h[0] = __floats2half2_rn(Whh_d[(0 * 256 + j) * 256 + ke], Whh_d[(0 * 256 + j) * 256 + ko]);
    w.h[1] = __floats2half2_rn(Whh_d[(1 * 256 + j) * 256 + ke], Whh_d[(1 * 256 + j) * 256 + ko]);
    w.h[2] = __floats2half2_rn(Whh_d[(2 * 256 + j) * 256 + ke], Whh_d[(2 * 256 + j) * 256 + ko]);
    w.h[3] = __floats2half2_rn(Whh_d[(3 * 256 + j) * 256 + ke], Whh_d[(3 * 256 + j) * 256 + ko]);
    ((uint4*)(ws + OFF_WD8))[idx] = w.u;
  }
}

// ---------------- attn_in[b][m] ----------------
__global__ void k_attn(const float* __restrict__ x, const float* __restrict__ W_ai,
                       const float* __restrict__ b_ai, float* __restrict__ ws) {
  __shared__ float wai[256];
  const int b = blockIdx.x, tid = threadIdx.x;  // 128 threads
  wai[tid] = W_ai[tid];
  wai[128 + tid] = W_ai[128 + tid];
  __syncthreads();
  if (tid < MM) {
    float acc = b_ai[0];
    const float* xp = x + (size_t)b * TT * MM + tid;
    #pragma unroll 8
    for (int t = 0; t < TT; ++t) acc = fmaf(xp[t * MM], wai[t], acc);
    ws[OFF_ATTN + b * MM + tid] = acc;
  }
}

// ---------------- encoder: 1024 threads, 2 batch rows, 256 steps, dot2 ----------------
__global__ __launch_bounds__(1024, 2) void k_encoder(
    const float* __restrict__ x, const float* __restrict__ b_ah,
    const float* __restrict__ W_a, const float* __restrict__ b_a,
    const float* __restrict__ bih_e, const float* __restrict__ bhh_e,
    float* __restrict__ ws) {
  __shared__ __align__(16) float aA[2048];     // p1 partials (q*256+j)*2+b; reused as scp[1536]
  __shared__ __align__(16) float4 gA[2048];    // gate partials (q*2+b)*256+j, 32 KB
  __shared__ __align__(16) float hpb[512];     // hid_proj packed 2h+b (fp32)
  __shared__ __align__(16) float wa2[256];
  __shared__ __align__(16) ushort hcb[2][512]; // fp16 [h;c] per batch
  __shared__ __align__(16) ushort uu[2][344];  // fp16 u=[wi(81);h(256);pad]
  const int tid = threadIdx.x;
  const int j = tid & 255, q = tid >> 8;
  const int b0 = blockIdx.x * 2, b1 = b0 + 1;

  if (tid < 256) wa2[tid] = W_a[tid];
  if (tid < 512) { hcb[0][tid] = 0; hcb[1][tid] = 0; }
  if (tid < 344) { uu[0][tid] = 0; uu[1][tid] = 0; }
  float bahr = 0.f; float4 bias4 = {0, 0, 0, 0};
  if (tid < 512) {
    bahr = b_ah[j];
    bias4.x = bih_e[j] + bhh_e[j];
    bias4.y = bih_e[256 + j] + bhh_e[256 + j];
    bias4.z = bih_e[512 + j] + bhh_e[512 + j];
    bias4.w = bih_e[768 + j] + bhh_e[768 + j];
  }
  float ai0 = 0.f, ai1 = 0.f;
  {
    int m = tid & 127;
    if (m < MM) {
      ai0 = ws[OFF_ATTN + b0 * MM + m];
      ai1 = ws[OFF_ATTN + b1 * MM + m];
    }
  }
  const float bav = b_a[0];
  float xc0 = 0.f, xc1 = 0.f;
  if (tid < 128) {
    int bb = (tid >= 64) ? b1 : b0;
    int lane = tid & 63;
    xc0 = x[((size_t)bb * TT) * MM + lane];
    xc1 = (lane < 17) ? x[((size_t)bb * TT) * MM + 64 + lane] : 0.f;
  }
  const unsigned int* __restrict__ Wah2u = (const unsigned int*)(ws + OFF_W2AH);
  const uint4* __restrict__ We8 = (const uint4*)(ws + OFF_WE8);
  const unsigned int* __restrict__ hc0 = (const unsigned int*)hcb[0];
  const unsigned int* __restrict__ hc1 = (const unsigned int*)hcb[1];
  const unsigned int* __restrict__ u0p = (const unsigned int*)uu[0];
  const unsigned int* __restrict__ u1p = (const unsigned int*)uu[1];
  float creg = 0.f;   // fp32 master c for tid<512
  __syncthreads();

  for (int t = 0; t < TT; ++t) {
    // ---- A: p1 partials (dot2) + LSTM h-part partials (dot2) ----
    {
      float a0 = 0.f, a1 = 0.f;
      const int kb = q * 64;
      #pragma unroll 8
      for (int i = 0; i < 64; ++i) {
        unsigned int w = Wah2u[(kb + i) * 256 + j];
        a0 = fdot2f(w, hc0[kb + i], a0);
        a1 = fdot2f(w, hc1[kb + i], a1);
      }
      aA[(q * 256 + j) * 2 + 0] = a0;
      aA[(q * 256 + j) * 2 + 1] = a1;
      float4 g0 = {0, 0, 0, 0}, g1 = {0, 0, 0, 0};
      const int ku0 = 41 + q * 32;
      #pragma unroll 4
      for (int i = 0; i < 32; ++i) {
        int ku = ku0 + i;
        uint4 wu = We8[ku * 256 + j];
        unsigned int ua = u0p[ku], ub = u1p[ku];
        g0.x = fdot2f(wu.x, ua, g0.x); g0.y = fdot2f(wu.y, ua, g0.y);
        g0.z = fdot2f(wu.z, ua, g0.z); g0.w = fdot2f(wu.w, ua, g0.w);
        g1.x = fdot2f(wu.x, ub, g1.x); g1.y = fdot2f(wu.y, ub, g1.y);
        g1.z = fdot2f(wu.z, ub, g1.z); g1.w = fdot2f(wu.w, ub, g1.w);
      }
      gA[(q * 2 + 0) * 256 + j] = g0;
      gA[(q * 2 + 1) * 256 + j] = g1;
    }
    __syncthreads();
    // ---- B: combine hid_proj ----
    if (tid < 512) {
      int b = tid >> 8, h = tid & 255;
      hpb[2 * h + b] = aA[(0 * 256 + h) * 2 + b] + aA[(1 * 256 + h) * 2 + b] +
                       aA[(2 * 256 + h) * 2 + b] + aA[(3 * 256 + h) * 2 + b] + bahr;
    }
    __syncthreads();
    // ---- C: score[m] partials (fp32 tanh) into aA ----
    {
      int m = tid & 127, tq = tid >> 7;
      if (m < MM) {
        float e0 = 0.f, e1 = 0.f;
        #pragma unroll 8
        for (int i = tq * 16; i < tq * 16 + 16; ++i) {
          float4 hv = *(const float4*)&hpb[i * 4];
          float2 wv = *(const float2*)&wa2[i * 2];
          e0 += ftanh(hv.x + ai0) * wv.x + ftanh(hv.z + ai0) * wv.y;
          e1 += ftanh(hv.y + ai1) * wv.x + ftanh(hv.w + ai1) * wv.y;
        }
        aA[(tq * 2 + 0) * 96 + m] = e0;
        aA[(tq * 2 + 1) * 96 + m] = e1;
      }
    }
    __syncthreads();
    // ---- D: softmax over m (no max-shift) + wi fp16 writes ----
    if (tid < 128) {
      int wv_id = tid >> 6, lane = tid & 63;
      float v0 = bav, v1 = bav;
      #pragma unroll
      for (int tq = 0; tq < 8; ++tq) {
        v0 += aA[(tq * 2 + wv_id) * 96 + lane];
        if (lane < 17) v1 += aA[(tq * 2 + wv_id) * 96 + 64 + lane];
      }
      float e0 = __expf(v0);
      float e1 = (lane < 17) ? __expf(v1) : 0.f;
      float sm = e0 + e1;
      #pragma unroll
      for (int d = 1; d < 64; d <<= 1) sm += __shfl_xor(sm, d);
      float inv = frcp(sm);
      uu[wv_id][lane] = f2h(e0 * inv * xc0);
      if (lane < 17) uu[wv_id][64 + lane] = f2h(e1 * inv * xc1);
      if (t < 255) {
        int bb = wv_id ? b1 : b0;
        xc0 = x[((size_t)bb * TT + t + 1) * MM + lane];
        xc1 = (lane < 17) ? x[((size_t)bb * TT + t + 1) * MM + 64 + lane] : 0.f;
      }
    }
    __syncthreads();
    // ---- E: LSTM wi-part partials, accumulate into own gA slots ----
    {
      const int kA = (q == 0) ? 0 : (q == 1) ? 11 : (q == 2) ? 21 : 31;
      const int kB = (q == 0) ? 11 : (q == 1) ? 21 : (q == 2) ? 31 : 41;
      float4 g0 = gA[(q * 2 + 0) * 256 + j];
      float4 g1 = gA[(q * 2 + 1) * 256 + j];
      for (int ku = kA; ku < kB; ++ku) {
        uint4 wu = We8[ku * 256 + j];
        unsigned int ua = u0p[ku], ub = u1p[ku];
        g0.x = fdot2f(wu.x, ua, g0.x); g0.y = fdot2f(wu.y, ua, g0.y);
        g0.z = fdot2f(wu.z, ua, g0.z); g0.w = fdot2f(wu.w, ua, g0.w);
        g1.x = fdot2f(wu.x, ub, g1.x); g1.y = fdot2f(wu.y, ub, g1.y);
        g1.z = fdot2f(wu.z, ub, g1.z); g1.w = fdot2f(wu.w, ub, g1.w);
      }
      gA[(q * 2 + 0) * 256 + j] = g0;
      gA[(q * 2 + 1) * 256 + j] = g1;
    }
    __syncthreads();
    // ---- F: gate combine + state update (fp32 regs, fp16 copies) ----
    if (tid < 512) {
      int b = tid >> 8, jj = tid & 255;
      float4 s0 = gA[(0 * 2 + b) * 256 + jj];
      float4 s1 = gA[(1 * 2 + b) * 256 + jj];
      float4 s2 = gA[(2 * 2 + b) * 256 + jj];
      float4 s3 = gA[(3 * 2 + b) * 256 + jj];
      float gi = s0.x + s1.x + s2.x + s3.x + bias4.x;
      float gf = s0.y + s1.y + s2.y + s3.y + bias4.y;
      float gg = s0.z + s1.z + s2.z + s3.z + bias4.z;
      float go = s0.w + s1.w + s2.w + s3.w + bias4.w;
      float c = fsig(gf) * creg + fsig(gi) * ftanh(gg);
      float h = fsig(go) * ftanh(c);
      creg = c;
      hcb[b][jj] = f2h(h);
      hcb[b][256 + jj] = f2h(c);
      uu[b][81 + jj] = f2h(h);
      ws[OFF_ENC + (((size_t)(b ? b1 : b0) * TT + t) * HEE + jj)] = h;
    }
    __syncthreads();
  }
}

// ---------------- encW[b][t] = enc[b,t,:] . W_fc[:256] ----------------
__global__ __launch_bounds__(256) void k_encw(const float* __restrict__ W_fc, float* __restrict__ ws) {
  const float* __restrict__ enc = ws + OFF_ENC;
  const int wv = threadIdx.x >> 6, lane = threadIdx.x & 63;
  float4 wfc = reinterpret_cast<const float4*>(W_fc)[lane];
  for (int r = blockIdx.x * 4 + wv; r < BB * TT; r += 4096) {
    float4 e = reinterpret_cast<const float4*>(enc + (size_t)r * HEE)[lane];
    float d = e.x * wfc.x + e.y * wfc.y + e.z * wfc.z + e.w * wfc.w;
    #pragma unroll
    for (int dd = 1; dd < 64; dd <<= 1) d += __shfl_xor(d, dd);
    if (lane == 0) ws[OFF_ENCW + r] = d;
  }
}

// ---------------- enc_proj fp16: epH[b][t'][h] ----------------
__global__ __launch_bounds__(256) void k_encproj(const float* __restrict__ W_d1, float* __restrict__ ws) {
  __shared__ __align__(16) float le[16][256];
  const int tid = threadIdx.x;
  const int b = blockIdx.x >> 4;
  const int t0 = (blockIdx.x & 15) * 16;
  const float* __restrict__ enc = ws + OFF_ENC;
  __half* __restrict__ epH = (__half*)(ws + OFF_EPI);
  #pragma unroll
  for (int rr = 0; rr < 16; ++rr)
    le[rr][tid] = enc[((size_t)b * TT + (t0 + rr)) * HEE + tid];
  __syncthreads();
  const float4* wrow = (const float4*)(W_d1 + (size_t)tid * 768 + 512);
  float acc[16];
  #pragma unroll
  for (int r = 0; r < 16; ++r) acc[r] = 0.f;
  for (int e4 = 0; e4 < 64; ++e4) {
    float4 w = wrow[e4];
    #pragma unroll
    for (int r = 0; r < 16; ++r) {
      float4 ev = *(const float4*)&le[r][e4 * 4];
      acc[r] += ev.x * w.x + ev.y * w.y + ev.z * w.z + ev.w * w.w;
    }
  }
  #pragma unroll
  for (int rr = 0; rr < 16; ++rr)
    epH[((size_t)b * TT + (t0 + rr)) * HEE + tid] = __float2half(acc[rr]);
}

// ---------------- decoder: 1024 threads, 2 sequential batch passes, dot2 ----------------
__global__ __launch_bounds__(1024) void k_decoder(
    const float* __restrict__ y_history, const float* __restrict__ b_d1,
    const float* __restrict__ W_d2, const float* __restrict__ b_d2,
    const float* __restrict__ W_fc, const float* __restrict__ b_fc,
    const float* __restrict__ Wih_d,
    const float* __restrict__ bih_d, const float* __restrict__ bhh_d,
    const float* __restrict__ W_ff, const float* __restrict__ b_ff,
    float* __restrict__ ws, float* __restrict__ out) {
  __shared__ __align__(16) ushort epL[65536];   // swizzled enc_proj, 128 KB
  __shared__ __align__(16) float aA[1024];      // matvec partials
  __shared__ __align__(16) float4 gA[1024];     // gate partials, 16 KB
  __shared__ __align__(16) ushort hc[512];      // fp16 [h;c]
  __shared__ __align__(16) float ddp[256];
  __shared__ __align__(16) float w2f[256];      // W_d2 fp32
  __shared__ __align__(16) float ybuf[256];
  __shared__ __align__(16) float awls[256];
  __shared__ float red[2][4];
  const int tid = threadIdx.x;
  const int tp = tid & 255, q = tid >> 8;
  const int lane = tid & 63, wvid = tid >> 6;
  const float wfcy = W_fc[256], bfc = b_fc[0], bd2v = b_d2[0], bffv = b_ff[0];

  if (tid < 256) w2f[tid] = W_d2[tid];
  const float bd1r = b_d1[tp];
  float4 biasd, wy;
  biasd.x = bih_d[tp] + bhh_d[tp];
  biasd.y = bih_d[256 + tp] + bhh_d[256 + tp];
  biasd.z = bih_d[512 + tp] + bhh_d[512 + tp];
  biasd.w = bih_d[768 + tp] + bhh_d[768 + tp];
  wy.x = Wih_d[tp]; wy.y = Wih_d[256 + tp]; wy.z = Wih_d[512 + tp]; wy.w = Wih_d[768 + tp];
  const float wffh = W_ff[tp], wffc = W_ff[256 + tp];

  const uint2* __restrict__ W4 = (const uint2*)(ws + OFF_W4D1);
  const uint4* __restrict__ Wd8 = (const uint4*)(ws + OFF_WD8);
  const uint4* __restrict__ epg = (const uint4*)(ws + OFF_EPI);
  const uint4* __restrict__ ep16 = (const uint4*)epL;
  const unsigned int* __restrict__ hc1 = (const unsigned int*)hc;
  const uint2* __restrict__ hc2 = (const uint2*)hc;

  for (int bp = 0; bp < 2; ++bp) {
    const int b = blockIdx.x * 2 + bp;
    if (tid < 512) hc[tid] = 0;
    if (tid < 255) ybuf[tid] = y_history[(size_t)b * 255 + tid] * wfcy + bfc;
    const float ewr = ws[OFF_ENCW + (size_t)b * 256 + tp];
    float hreg = 0.f, creg = 0.f;
    {
      const uint4* src = epg + (size_t)b * 8192;
      #pragma unroll
      for (int k = 0; k < 8; ++k) {
        int g = k * 1024 + tid;
        int t = g >> 5, c = g & 31;
        ((uint4*)epL)[(g & ~31) | (c ^ (t & 31))] = src[g];
      }
    }
    __syncthreads();

    for (int s = 0; s < 255; ++s) {
      // ---- A: p1 partials (dot2) + Whh gate partials (dot2) ----
      {
        float a0 = 0.f;
        const int k4b = q * 32;
        #pragma unroll 8
        for (int i = 0; i < 32; ++i) {
          int k4 = k4b + i;
          uint2 wu = W4[k4 * 256 + tp];
          uint2 hv = hc2[k4];
          a0 = fdot2f(wu.x, hv.x, a0);
          a0 = fdot2f(wu.y, hv.y, a0);
        }
        aA[q * 256 + tp] = a0;
        float4 g = {0, 0, 0, 0};
        const int k2b = q * 32;
        #pragma unroll 4
        for (int i = 0; i < 32; ++i) {
          int k2 = k2b + i;
          uint4 wu = Wd8[k2 * 256 + tp];
          unsigned int u2 = hc1[k2];
          g.x = fdot2f(wu.x, u2, g.x); g.y = fdot2f(wu.y, u2, g.y);
          g.z = fdot2f(wu.z, u2, g.z); g.w = fdot2f(wu.w, u2, g.w);
        }
        gA[q * 256 + tp] = g;
      }
      __syncthreads();
      // ---- B: d combine ----
      if (tid < 256)
        ddp[tid] = aA[tid] + aA[256 + tid] + aA[512 + tid] + aA[768 + tid] + bd1r;
      __syncthreads();
      // ---- C: score partials (fp32 tanh, fp32 w2 broadcast) ----
      {
        float q0 = 0.f;
        const int rowbase = tp * 32, sw = tp & 31;
        #pragma unroll
        for (int k = 0; k < 8; ++k) {
          uint4 e0u = ep16[rowbase + ((q * 8 + k) ^ sw)];
          const int h8 = q * 64 + k * 8;
          float4 wfa = *(const float4*)&w2f[h8];
          float4 wfb = *(const float4*)&w2f[h8 + 4];
          float4 dva = *(const float4*)&ddp[h8];
          float4 dvb = *(const float4*)&ddp[h8 + 4];
          const __half2* e0h = (const __half2*)&e0u;
          float2 ea = __half22float2(e0h[0]);
          q0 += wfa.x * ftanh(ea.x + dva.x) + wfa.y * ftanh(ea.y + dva.y);
          float2 eb = __half22float2(e0h[1]);
          q0 += wfa.z * ftanh(eb.x + dva.z) + wfa.w * ftanh(eb.y + dva.w);
          float2 ec = __half22float2(e0h[2]);
          q0 += wfb.x * ftanh(ec.x + dvb.x) + wfb.y * ftanh(ec.y + dvb.y);
          float2 ed = __half22float2(e0h[3]);
          q0 += wfb.z * ftanh(ed.x + dvb.z) + wfb.w * ftanh(ed.y + dvb.w);
        }
        aA[q * 256 + tp] = q0;
      }
      __syncthreads();
      // ---- D: softmax (no max-shift) partial reductions ----
      float esc = 0.f;
      if (tid < 256) {
        float sc = aA[tid] + aA[256 + tid] + aA[512 + tid] + aA[768 + tid] + bd2v;
        esc = __expf(sc);
        float den = esc, num = esc * ewr;
        #pragma unroll
        for (int d = 1; d < 64; d <<= 1) { den += __shfl_xor(den, d); num += __shfl_xor(num, d); }
        if (lane == 0) { red[0][wvid] = den; red[1][wvid] = num; }
      }
      __syncthreads();
      // ---- E: y + gate combine + state update ----
      if (tid < 256) {
        float den = red[0][0] + red[0][1] + red[0][2] + red[0][3];
        float num = red[1][0] + red[1][1] + red[1][2] + red[1][3];
        float inv = frcp(den);
        float y = num * inv + ybuf[s];
        if (s == 254) awls[tp] = esc * inv;
        float4 s0 = gA[tp], s1 = gA[256 + tp], s2 = gA[512 + tp], s3 = gA[768 + tp];
        float gi = s0.x + s1.x + s2.x + s3.x + wy.x * y + biasd.x;
        float gf = s0.y + s1.y + s2.y + s3.y + wy.y * y + biasd.y;
        float gg = s0.z + s1.z + s2.z + s3.z + wy.z * y + biasd.z;
        float go = s0.w + s1.w + s2.w + s3.w + wy.w * y + biasd.w;
        float c = fsig(gf) * creg + fsig(gi) * ftanh(gg);
        float h = fsig(go) * ftanh(c);
        creg = c; hreg = h;
        hc[tp] = f2h(h);
        hc[256 + tp] = f2h(c);
      }
      __syncthreads();
    }

    // ---- finale: ctx with last-step aw + output ----
    {
      float c0 = 0.f;
      const float* __restrict__ ep = ws + OFF_ENC + (size_t)b * TT * HEE;
      for (int t = q * 64; t < q * 64 + 64; ++t)
        c0 = fmaf(awls[t], ep[(size_t)t * HEE + tp], c0);
      aA[q * 256 + tp] = c0;
    }
    __syncthreads();
    if (tid < 256) {
      float ctx = aA[tid] + aA[256 + tid] + aA[512 + tid] + aA[768 + tid];
      float p = hreg * wffh + ctx * wffc;
      #pragma unroll
      for (int d = 1; d < 64; d <<= 1) p += __shfl_xor(p, d);
      if (lane == 0) red[0][wvid] = p;
    }
    __syncthreads();
    if (tid == 0) out[b] = red[0][0] + red[0][1] + red[0][2] + red[0][3] + bffv;
    __syncthreads();
  }
}

extern "C" void kernel_launch(void* const* d_in, const int* in_sizes, int n_in,
                              void* d_out, int out_size, void* d_ws, size_t ws_size,
                              hipStream_t stream) {
  if (ws_size < (size_t)WS_FLOATS * sizeof(float)) return;
  const float* x     = (const float*)d_in[0];
  const float* y_h   = (const float*)d_in[1];
  const float* W_ah  = (const float*)d_in[2];
  const float* b_ah  = (const float*)d_in[3];
  const float* W_ai  = (const float*)d_in[4];
  const float* b_ai  = (const float*)d_in[5];
  const float* W_a   = (const float*)d_in[6];
  const float* b_a   = (const float*)d_in[7];
  const float* Wih_e = (const float*)d_in[8];
  const float* Whh_e = (const float*)d_in[9];
  const float* bih_e = (const float*)d_in[10];
  const float* bhh_e = (const float*)d_in[11];
  const float* W_d1  = (const float*)d_in[12];
  const float* b_d1  = (const float*)d_in[13];
  const float* W_d2  = (const float*)d_in[14];
  const float* b_d2  = (const float*)d_in[15];
  const float* W_fc  = (const float*)d_in[16];
  const float* b_fc  = (const float*)d_in[17];
  const float* Wih_d = (const float*)d_in[18];
  const float* Whh_d = (const float*)d_in[19];
  const float* bih_d = (const float*)d_in[20];
  const float* bhh_d = (const float*)d_in[21];
  const float* W_ff  = (const float*)d_in[22];
  const float* b_ff  = (const float*)d_in[23];
  float* ws  = (float*)d_ws;
  float* out = (float*)d_out;

  k_prep<<<256, 512, 0, stream>>>(W_ah, Wih_e, Whh_e, W_d1, Wih_d, Whh_d, ws);
  k_attn<<<512, 128, 0, stream>>>(x, W_ai, b_ai, ws);
  k_encoder<<<256, 1024, 0, stream>>>(x, b_ah, W_a, b_a, bih_e, bhh_e, ws);
  k_encw<<<1024, 256, 0, stream>>>(W_fc, ws);
  k_encproj<<<8192, 256, 0, stream>>>(W_d1, ws);
  k_decoder<<<256, 1024, 0, stream>>>(y_h, b_d1, W_d2, b_d2, W_fc, b_fc,
                                      Wih_d, bih_d, bhh_d, W_ff, b_ff, ws, out);
}